// Round 1
// baseline (2421.958 us; speedup 1.0000x reference)
//
#include <hip/hip_runtime.h>
#include <hip/hip_bf16.h>

#define BB 64
#define NN 256
#define DD 512
#define EE 10

typedef __bf16 bf16x8 __attribute__((ext_vector_type(8)));
typedef unsigned short ushort8v __attribute__((ext_vector_type(8)));
typedef unsigned int uint4v __attribute__((ext_vector_type(4)));
typedef float floatx4 __attribute__((ext_vector_type(4)));

__device__ __forceinline__ unsigned short f2b(float f) {
    union { float f; unsigned u; } x; x.f = f;
    unsigned r = x.u + 0x7FFFu + ((x.u >> 16) & 1u);
    return (unsigned short)(r >> 16);
}
__device__ __forceinline__ float b2f(unsigned short u) {
    union { unsigned u; float f; } x; x.u = ((unsigned)u) << 16;
    return x.f;
}

// ---------------- K0a: convert W_edge (10*512*512) ++ W_self (512*512) -> bf16 table
__global__ void k_wconv(const float* __restrict__ W_edge,
                        const float* __restrict__ W_self,
                        unsigned short* __restrict__ W_all) {
    size_t i = (size_t)blockIdx.x * 256 + threadIdx.x; // grid exactly 11*512*512/256
    float v = (i < (size_t)EE * DD * DD) ? W_edge[i] : W_self[i - (size_t)EE * DD * DD];
    W_all[i] = f2b(v);
}

// ---------------- K0b: pack graphs bits + recip(neigh). One block per (b,n), 256 thr.
__global__ void k_graph(const int* __restrict__ adj, const int* __restrict__ mask,
                        unsigned* __restrict__ packed, float* __restrict__ recip) {
    int b = blockIdx.x >> 8;
    int n = blockIdx.x & 255;
    int lane = threadIdx.x & 63;
    int wv   = threadIdx.x >> 6;   // 0..3
    int m = wv * 64 + lane;
    int ok = (mask[b * NN + n] != 0) & (mask[b * NN + m] != 0) & (m != n);
    __shared__ int cnt_s[4];
    int total = 0;
    #pragma unroll
    for (int e = 0; e < EE; e++) {
        int a = adj[(((size_t)e * BB + b) * NN + n) * NN + m];
        int bit = ok & (a != 0);
        unsigned long long bal = __ballot(bit);
        if (lane == 0) {
            unsigned* dst = packed + (((size_t)e * BB + b) * NN + n) * 8 + wv * 2;
            dst[0] = (unsigned)bal;
            dst[1] = (unsigned)(bal >> 32);
        }
        total += bit;
    }
    for (int off = 32; off; off >>= 1) total += __shfl_down(total, off);
    if (lane == 0) cnt_s[wv] = total;
    __syncthreads();
    if (threadIdx.x == 0) {
        int c = cnt_s[0] + cnt_s[1] + cnt_s[2] + cnt_s[3];
        recip[b * NN + n] = 1.0f / (float)(c < 1 ? 1 : c);
    }
}

// ---------------- K1a: gate w = sigmoid(node . W_nw + b). One wave per (b,n).
template<int TI>
__global__ void k_gate(const float* __restrict__ xf, const unsigned short* __restrict__ xbin,
                       const float* __restrict__ W_nw, const float* __restrict__ b_nw,
                       float* __restrict__ w_buf, float* __restrict__ w_out) {
    int idx = blockIdx.x * 4 + (threadIdx.x >> 6);  // 0..16383 = b*256+n
    int lane = threadIdx.x & 63;
    size_t base = (size_t)idx * DD + lane * 8;
    const floatx4* wp = (const floatx4*)(W_nw + lane * 8);
    floatx4 w0 = wp[0], w1 = wp[1];
    float s = 0.f;
    if (TI == 0) {
        const floatx4* xp = (const floatx4*)(xf + base);
        floatx4 a0 = xp[0], a1 = xp[1];
        #pragma unroll
        for (int j = 0; j < 4; j++) s += a0[j] * w0[j] + a1[j] * w1[j];
    } else {
        ushort8v u = *(const ushort8v*)(xbin + base);
        #pragma unroll
        for (int j = 0; j < 8; j++) {
            float wj = (j < 4) ? w0[j] : w1[j - 4];
            s += b2f(u[j]) * wj;
        }
    }
    for (int off = 32; off; off >>= 1) s += __shfl_down(s, off);
    if (lane == 0) {
        float v = 1.f / (1.f + __expf(-(s + b_nw[0])));
        w_buf[idx] = v;
        int b = idx >> 8, n = idx & 255;
        w_out[(b * 2 + TI) * NN + n] = v;
    }
}

// ---------------- K1b: wT[b][d][n] = w[b][n]*x[b][n][d] (bf16, transposed); t=0 also xb0.
template<int TI>
__global__ void k_trans(const float* __restrict__ xf, const unsigned short* __restrict__ xbin,
                        const float* __restrict__ w_buf,
                        unsigned short* __restrict__ wT, unsigned short* __restrict__ xb0) {
    int bid = blockIdx.x;              // 64*4*8 = 2048
    int b  = bid >> 5;
    int nt = (bid >> 3) & 3;
    int dt = bid & 7;
    int n0 = nt * 64, d0 = dt * 64;
    __shared__ float tile[64][65];
    int j  = threadIdx.x & 63;         // d
    int i0 = threadIdx.x >> 6;
    #pragma unroll
    for (int ii = 0; ii < 16; ii++) {
        int i = i0 * 16 + ii;          // n
        size_t gi = ((size_t)b * NN + n0 + i) * DD + d0 + j;
        float v = (TI == 0) ? xf[gi] : b2f(xbin[gi]);
        tile[i][j] = v;
        if (TI == 0) xb0[gi] = f2b(v);
    }
    __syncthreads();
    int i2 = threadIdx.x & 63;         // n (coalesced writes)
    int j0 = threadIdx.x >> 6;
    float wv = w_buf[b * NN + n0 + i2];
    #pragma unroll
    for (int jj = 0; jj < 16; jj++) {
        int j2 = j0 * 16 + jj;         // d
        wT[((size_t)b * DD + d0 + j2) * NN + n0 + i2] = f2b(tile[i2][j2] * wv);
    }
}

// ---------------- K2: heavy fused kernel. Block = 512 thr (8 waves), one 32x512 out tile.
// agg = sum_e (G_e @ wnode)*recip @ W_e^T ; + node @ W_self^T ; +b_self ; relu.
template<int TI>
__global__ __launch_bounds__(512, 4)
void k2_heavy(const unsigned short* __restrict__ wT,    // [B][D][N]
              const unsigned short* __restrict__ xb,    // [B][N][D]
              const unsigned short* __restrict__ W_all, // [11][D][D] (d_out,k)
              const unsigned* __restrict__ packed,      // [E][B][N][8]
              const float* __restrict__ recip,          // [B][N]
              const float* __restrict__ b_self,         // [D]
              unsigned short* __restrict__ out_bf16,    // t=0
              float* __restrict__ out_f32) {            // t=1
    __shared__ unsigned short Tt[32 * 520];             // pad 512->520 (16B-aligned rows)
    int bid = blockIdx.x;          // 512 blocks: b = bid&63 keeps a b's tiles on one XCD
    int b  = bid & 63;
    int r0 = (bid >> 6) * 32;
    int w    = threadIdx.x >> 6;
    int lane = threadIdx.x & 63;
    int wrow = (w & 1) * 16;       // row half within 32
    int wcol = (w >> 1) * 128;     // col quarter within 512
    int lc = lane & 15;
    int lk = lane >> 4;
    int shift = lk * 8;

    floatx4 acc[8];
    #pragma unroll
    for (int i = 0; i < 8; i++) acc[i] = (floatx4)(0.0f);

    float rn[4];
    #pragma unroll
    for (int r = 0; r < 4; r++) rn[r] = recip[b * NN + r0 + wrow + lk * 4 + r];

    int arow_g = r0 + wrow + lc;   // A row (global n) for this lane

    for (int e = 0; e < EE; e++) {
        // ---- stage 1: T_e tile (32x512) = G_e @ wnode, rows scaled by recip ----
        floatx4 acc3[8];
        #pragma unroll
        for (int i = 0; i < 8; i++) acc3[i] = (floatx4)(0.0f);
        const uint4v* pp = (const uint4v*)(packed + (((size_t)e * BB + b) * NN + arow_g) * 8);
        uint4v pwa = pp[0], pwb = pp[1];
        unsigned pw[8] = {pwa[0], pwa[1], pwa[2], pwa[3], pwb[0], pwb[1], pwb[2], pwb[3]};
        #pragma unroll
        for (int ms = 0; ms < 8; ms++) {
            unsigned byte = (pw[ms] >> shift) & 0xFFu;
            uint4v av;
            #pragma unroll
            for (int p = 0; p < 4; p++) {
                unsigned b2 = (byte >> (2 * p)) & 3u;
                av[p] = ((b2 & 1u) ? 0x3F80u : 0u) | ((b2 & 2u) ? 0x3F800000u : 0u);
            }
            bf16x8 afrag = __builtin_bit_cast(bf16x8, av);
            int m0 = ms * 32 + lk * 8;
            #pragma unroll
            for (int cb = 0; cb < 8; cb++) {
                int kcol = wcol + cb * 16 + lc;
                bf16x8 bfrag = __builtin_bit_cast(bf16x8,
                    *(const ushort8v*)(wT + ((size_t)b * DD + kcol) * NN + m0));
                acc3[cb] = __builtin_amdgcn_mfma_f32_16x16x32_bf16(afrag, bfrag, acc3[cb], 0, 0, 0);
            }
        }
        __syncthreads();   // previous e's stage-2 reads of Tt are done
        #pragma unroll
        for (int cb = 0; cb < 8; cb++) {
            int col = wcol + cb * 16 + lc;
            #pragma unroll
            for (int r = 0; r < 4; r++) {
                int row = wrow + lk * 4 + r;
                Tt[row * 520 + col] = f2b(acc3[cb][r] * rn[r]);
            }
        }
        __syncthreads();
        // ---- stage 2: acc += Tt(rows wrow..+15) @ W_e^T (cols wcol..+127) ----
        #pragma unroll
        for (int ks = 0; ks < 16; ks++) {
            int k0 = ks * 32 + lk * 8;
            bf16x8 afrag = __builtin_bit_cast(bf16x8,
                *(const ushort8v*)(Tt + (wrow + lc) * 520 + k0));
            #pragma unroll
            for (int cb = 0; cb < 8; cb++) {
                int dcol = wcol + cb * 16 + lc;
                bf16x8 bfrag = __builtin_bit_cast(bf16x8,
                    *(const ushort8v*)(W_all + ((size_t)e * DD + dcol) * DD + k0));
                acc[cb] = __builtin_amdgcn_mfma_f32_16x16x32_bf16(afrag, bfrag, acc[cb], 0, 0, 0);
            }
        }
    }
    // ---- self path: e=10, A direct from node bf16 ----
    #pragma unroll
    for (int ks = 0; ks < 16; ks++) {
        int k0 = ks * 32 + lk * 8;
        bf16x8 afrag = __builtin_bit_cast(bf16x8,
            *(const ushort8v*)(xb + ((size_t)b * NN + arow_g) * DD + k0));
        #pragma unroll
        for (int cb = 0; cb < 8; cb++) {
            int dcol = wcol + cb * 16 + lc;
            bf16x8 bfrag = __builtin_bit_cast(bf16x8,
                *(const ushort8v*)(W_all + ((size_t)EE * DD + dcol) * DD + k0));
            acc[cb] = __builtin_amdgcn_mfma_f32_16x16x32_bf16(afrag, bfrag, acc[cb], 0, 0, 0);
        }
    }
    // ---- epilogue: +b_self, relu, store ----
    #pragma unroll
    for (int cb = 0; cb < 8; cb++) {
        int dcol = wcol + cb * 16 + lc;
        float bs = b_self[dcol];
        #pragma unroll
        for (int r = 0; r < 4; r++) {
            int row = r0 + wrow + lk * 4 + r;
            float v = acc[cb][r] + bs;
            v = v > 0.f ? v : 0.f;
            size_t gi = ((size_t)b * NN + row) * DD + dcol;
            if (TI == 0) out_bf16[gi] = f2b(v);
            else         out_f32[gi] = v;
        }
    }
}

extern "C" void kernel_launch(void* const* d_in, const int* in_sizes, int n_in,
                              void* d_out, int out_size, void* d_ws, size_t ws_size,
                              hipStream_t stream) {
    const float* node   = (const float*)d_in[0];
    const float* W_nw   = (const float*)d_in[1];
    const float* b_nw   = (const float*)d_in[2];
    const float* W_self = (const float*)d_in[3];
    const float* b_self = (const float*)d_in[4];
    const float* W_edge = (const float*)d_in[5];
    const int*   mask   = (const int*)d_in[6];
    const int*   adj    = (const int*)d_in[7];
    float* out = (float*)d_out;
    float* out_w = out + (size_t)BB * NN * DD;   // all_weight region [B][2][N]

    char* ws = (char*)d_ws;
    size_t off = 0;
    unsigned short* W_all = (unsigned short*)(ws + off); off += (size_t)11 * DD * DD * 2;      // 5.77 MB
    unsigned short* wT    = (unsigned short*)(ws + off); off += (size_t)BB * DD * NN * 2;      // 16.78 MB
    unsigned short* xb0   = (unsigned short*)(ws + off); off += (size_t)BB * NN * DD * 2;      // 16.78 MB
    unsigned short* xb1   = (unsigned short*)(ws + off); off += (size_t)BB * NN * DD * 2;      // 16.78 MB
    unsigned*       packed= (unsigned*)(ws + off);       off += (size_t)EE * BB * NN * 8 * 4;  // 5.24 MB
    float*          recip = (float*)(ws + off);          off += (size_t)BB * NN * 4;
    float*          w_buf = (float*)(ws + off);          off += (size_t)BB * NN * 4;

    k_wconv<<<dim3(11264), dim3(256), 0, stream>>>(W_edge, W_self, W_all);
    k_graph<<<dim3(16384), dim3(256), 0, stream>>>(adj, mask, packed, recip);

    // iteration 0
    k_gate<0><<<dim3(4096), dim3(256), 0, stream>>>(node, nullptr, W_nw, b_nw, w_buf, out_w);
    k_trans<0><<<dim3(2048), dim3(256), 0, stream>>>(node, nullptr, w_buf, wT, xb0);
    k2_heavy<0><<<dim3(512), dim3(512), 0, stream>>>(wT, xb0, W_all, packed, recip, b_self, xb1, nullptr);

    // iteration 1
    k_gate<1><<<dim3(4096), dim3(256), 0, stream>>>(nullptr, xb1, W_nw, b_nw, w_buf, out_w);
    k_trans<1><<<dim3(2048), dim3(256), 0, stream>>>(nullptr, xb1, w_buf, wT, xb0 /*unused*/);
    k2_heavy<1><<<dim3(512), dim3(512), 0, stream>>>(wT, xb1, W_all, packed, recip, b_self, nullptr, out);
}

// Round 2
// 2363.916 us; speedup vs baseline: 1.0246x; 1.0246x over previous
//
#include <hip/hip_runtime.h>
#include <hip/hip_bf16.h>

#define BB 64
#define NN 256
#define DD 512
#define EE 10

typedef __bf16 bf16x8 __attribute__((ext_vector_type(8)));
typedef unsigned short ushort8v __attribute__((ext_vector_type(8)));
typedef unsigned int uint4v __attribute__((ext_vector_type(4)));
typedef float floatx4 __attribute__((ext_vector_type(4)));

__device__ __forceinline__ unsigned short f2b(float f) {
    union { float f; unsigned u; } x; x.f = f;
    unsigned r = x.u + 0x7FFFu + ((x.u >> 16) & 1u);
    return (unsigned short)(r >> 16);
}
__device__ __forceinline__ float b2f(unsigned short u) {
    union { unsigned u; float f; } x; x.u = ((unsigned)u) << 16;
    return x.f;
}

// ---------------- K0a: build W_frag in MFMA-B fragment order.
// W_frag[t]*8 where t = ((e*32+cfg)*16+ks)*64 + lane; lane=(lk*16+lc);
// element j = W[e][dout=cfg*16+lc][k=ks*32+lk*8+j]; e==10 -> W_self.
__global__ void k_wconv(const float* __restrict__ W_edge,
                        const float* __restrict__ W_self,
                        unsigned short* __restrict__ Wf) {
    int t = blockIdx.x * 256 + threadIdx.x;   // grid 1408 -> 360448 exact
    int lane = t & 63;
    int ks   = (t >> 6) & 15;
    int cfg  = (t >> 10) & 31;
    int e    = t >> 15;                       // 0..10
    int lc = lane & 15, lk = lane >> 4;
    int dout = cfg * 16 + lc;
    int k    = ks * 32 + lk * 8;
    const float* src = (e < EE) ? (W_edge + ((size_t)e * DD + dout) * DD + k)
                                : (W_self + (size_t)dout * DD + k);
    ushort8v o;
    #pragma unroll
    for (int j = 0; j < 8; j++) o[j] = f2b(src[j]);
    *(ushort8v*)(Wf + (size_t)t * 8) = o;
}

// ---------------- K0b: pack graphs bits + recip(neigh). One block per (b,n).
__global__ void k_graph(const int* __restrict__ adj, const int* __restrict__ mask,
                        unsigned* __restrict__ packed, float* __restrict__ recip) {
    int b = blockIdx.x >> 8;
    int n = blockIdx.x & 255;
    int lane = threadIdx.x & 63;
    int wv   = threadIdx.x >> 6;   // 0..3
    int m = wv * 64 + lane;
    int ok = (mask[b * NN + n] != 0) & (mask[b * NN + m] != 0) & (m != n);
    __shared__ int cnt_s[4];
    int total = 0;
    #pragma unroll
    for (int e = 0; e < EE; e++) {
        int a = adj[(((size_t)e * BB + b) * NN + n) * NN + m];
        int bit = ok & (a != 0);
        unsigned long long bal = __ballot(bit);
        if (lane == 0) {
            unsigned* dst = packed + (((size_t)e * BB + b) * NN + n) * 8 + wv * 2;
            dst[0] = (unsigned)bal;
            dst[1] = (unsigned)(bal >> 32);
        }
        total += bit;
    }
    for (int off = 32; off; off >>= 1) total += __shfl_down(total, off);
    if (lane == 0) cnt_s[wv] = total;
    __syncthreads();
    if (threadIdx.x == 0) {
        int c = cnt_s[0] + cnt_s[1] + cnt_s[2] + cnt_s[3];
        recip[b * NN + n] = 1.0f / (float)(c < 1 ? 1 : c);
    }
}

// ---------------- K1a: gate w = sigmoid(node . W_nw + b). One wave per (b,n).
template<int TI>
__global__ void k_gate(const float* __restrict__ xf, const unsigned short* __restrict__ xbin,
                       const float* __restrict__ W_nw, const float* __restrict__ b_nw,
                       float* __restrict__ w_buf, float* __restrict__ w_out) {
    int idx = blockIdx.x * 4 + (threadIdx.x >> 6);
    int lane = threadIdx.x & 63;
    size_t base = (size_t)idx * DD + lane * 8;
    const floatx4* wp = (const floatx4*)(W_nw + lane * 8);
    floatx4 w0 = wp[0], w1 = wp[1];
    float s = 0.f;
    if (TI == 0) {
        const floatx4* xp = (const floatx4*)(xf + base);
        floatx4 a0 = xp[0], a1 = xp[1];
        #pragma unroll
        for (int j = 0; j < 4; j++) s += a0[j] * w0[j] + a1[j] * w1[j];
    } else {
        ushort8v u = *(const ushort8v*)(xbin + base);
        #pragma unroll
        for (int j = 0; j < 8; j++) {
            float wj = (j < 4) ? w0[j] : w1[j - 4];
            s += b2f(u[j]) * wj;
        }
    }
    for (int off = 32; off; off >>= 1) s += __shfl_down(s, off);
    if (lane == 0) {
        float v = 1.f / (1.f + __expf(-(s + b_nw[0])));
        w_buf[idx] = v;
        int b = idx >> 8, n = idx & 255;
        w_out[(b * 2 + TI) * NN + n] = v;
    }
}

// ---------------- K1b: build wTf (stage-1 B fragments) = w[b][m]*node[b][m][d], bf16.
// wTf[(((b*8+mblk)*32+dblk)*64+lane)*8 + j] = wnode[b][mblk*32+lk*8+j][dblk*16+lc].
template<int TI>
__global__ void k_transf(const float* __restrict__ xf, const unsigned short* __restrict__ xbin,
                         const float* __restrict__ w_buf,
                         unsigned short* __restrict__ wTf, unsigned short* __restrict__ xb0) {
    int bid = blockIdx.x;              // 64*4*8 = 2048
    int b  = bid >> 5;
    int nt = (bid >> 3) & 3;
    int dt = bid & 7;
    __shared__ float tile[64][65];
    __shared__ float ws[64];
    int j  = threadIdx.x & 63;         // d
    int i0 = threadIdx.x >> 6;
    if (threadIdx.x < 64) ws[threadIdx.x] = w_buf[b * NN + nt * 64 + threadIdx.x];
    #pragma unroll
    for (int ii = 0; ii < 16; ii++) {
        int i = i0 * 16 + ii;          // n local
        size_t gi = ((size_t)b * NN + nt * 64 + i) * DD + dt * 64 + j;
        float v = (TI == 0) ? xf[gi] : b2f(xbin[gi]);
        tile[i][j] = v;
        if (TI == 0) xb0[gi] = f2b(v);
    }
    __syncthreads();
    #pragma unroll
    for (int cc = 0; cc < 2; cc++) {
        int c = threadIdx.x + 256 * cc;   // c = (mb*4+db)*64 + lane
        int lane = c & 63;
        int db   = (c >> 6) & 3;
        int mb   = c >> 8;
        int lc = lane & 15, lk = lane >> 4;
        int nloc = mb * 32 + lk * 8;
        int dloc = db * 16 + lc;
        ushort8v o;
        #pragma unroll
        for (int jj = 0; jj < 8; jj++) o[jj] = f2b(tile[nloc + jj][dloc] * ws[nloc + jj]);
        size_t gi = ((((size_t)b * 8 + nt * 2 + mb) * 32 + dt * 4 + db) * 64 + lane) * 8;
        *(ushort8v*)(wTf + gi) = o;
    }
}

// ---------------- K2: fused heavy kernel. 512 thr (8 waves), M=64 rows x 512 cols out.
// Waves: rf = w&3 (16-row frag), ch = w>>2 (256-col half).
template<int TI>
__global__ __launch_bounds__(512, 2)
void k2_heavy(const unsigned short* __restrict__ wTf,   // frag-order wnode
              const unsigned short* __restrict__ xb,    // [B][N][D] bf16 (self A)
              const unsigned short* __restrict__ Wf,    // frag-order weights [11]
              const unsigned* __restrict__ packed,      // [E][B][N][8]
              const float* __restrict__ recip,          // [B][N]
              const float* __restrict__ b_self,         // [D]
              unsigned short* __restrict__ out_bf16,    // t=0
              float* __restrict__ out_f32) {            // t=1
    __shared__ __attribute__((aligned(16))) unsigned short Tt[64 * 520]; // pad 512->520
    int bid = blockIdx.x;          // 256 blocks
    int b  = bid & 63;
    int rt = bid >> 6;
    int w    = threadIdx.x >> 6;
    int lane = threadIdx.x & 63;
    int rf = w & 3;
    int ch = w >> 2;
    int lc = lane & 15;
    int lk = lane >> 4;
    int r0 = rt * 64;
    int arow = r0 + rf * 16 + lc;      // A row for this lane (stage1 bits & self)

    float rn[4];
    #pragma unroll
    for (int r = 0; r < 4; r++) rn[r] = recip[b * NN + r0 + rf * 16 + lk * 4 + r];

    floatx4 acc2[16];
    #pragma unroll
    for (int i = 0; i < 16; i++) acc2[i] = (floatx4)(0.0f);

    #pragma unroll 1
    for (int e = 0; e < EE; e++) {
        const uint4v* pp = (const uint4v*)(packed + (((size_t)e * BB + b) * NN + arow) * 8);
        uint4v pwa = pp[0], pwb = pp[1];
        unsigned pw[8] = {pwa[0], pwa[1], pwa[2], pwa[3], pwb[0], pwb[1], pwb[2], pwb[3]};
        // ---- stage 1: acc3[cf] (16 rows x 256 cols per wave), K=256 over m ----
        floatx4 acc3[16];
        #pragma unroll
        for (int i = 0; i < 16; i++) acc3[i] = (floatx4)(0.0f);
        #pragma unroll
        for (int ms = 0; ms < 8; ms++) {
            unsigned byte = (pw[ms] >> (lk * 8)) & 0xFFu;
            uint4v av;
            #pragma unroll
            for (int p = 0; p < 4; p++) {
                unsigned b2 = (byte >> (2 * p)) & 3u;
                av[p] = ((b2 & 1u) ? 0x3F80u : 0u) | ((b2 & 2u) ? 0x3F800000u : 0u);
            }
            bf16x8 afrag = __builtin_bit_cast(bf16x8, av);
            #pragma unroll
            for (int cf = 0; cf < 16; cf++) {
                int dblk = ch * 16 + cf;
                bf16x8 bfrag = __builtin_bit_cast(bf16x8,
                    *(const ushort8v*)(wTf + ((((size_t)b * 8 + ms) * 32 + dblk) * 64 + lane) * 8));
                acc3[cf] = __builtin_amdgcn_mfma_f32_16x16x32_bf16(afrag, bfrag, acc3[cf], 0, 0, 0);
            }
        }
        __syncthreads();   // previous e's stage-2 done reading Tt
        #pragma unroll
        for (int cf = 0; cf < 16; cf++) {
            int col = ch * 256 + cf * 16 + lc;
            #pragma unroll
            for (int r = 0; r < 4; r++) {
                int row = rf * 16 + lk * 4 + r;
                Tt[row * 520 + col] = f2b(acc3[cf][r] * rn[r]);
            }
        }
        __syncthreads();
        // ---- stage 2: acc2 += Tt(rows rf) @ W_e^T (cols ch) ----
        #pragma unroll
        for (int ks = 0; ks < 16; ks++) {
            bf16x8 afrag = __builtin_bit_cast(bf16x8,
                *(const ushort8v*)(Tt + (rf * 16 + lc) * 520 + ks * 32 + lk * 8));
            #pragma unroll
            for (int cf = 0; cf < 16; cf++) {
                int cfg = ch * 16 + cf;
                bf16x8 bfrag = __builtin_bit_cast(bf16x8,
                    *(const ushort8v*)(Wf + ((((size_t)e * 32 + cfg) * 16 + ks) * 64 + lane) * 8));
                acc2[cf] = __builtin_amdgcn_mfma_f32_16x16x32_bf16(afrag, bfrag, acc2[cf], 0, 0, 0);
            }
        }
    }
    // ---- self path (e=10): A direct from xb ----
    #pragma unroll
    for (int ks = 0; ks < 16; ks++) {
        bf16x8 afrag = __builtin_bit_cast(bf16x8,
            *(const ushort8v*)(xb + ((size_t)b * NN + arow) * DD + ks * 32 + lk * 8));
        #pragma unroll
        for (int cf = 0; cf < 16; cf++) {
            int cfg = ch * 16 + cf;
            bf16x8 bfrag = __builtin_bit_cast(bf16x8,
                *(const ushort8v*)(Wf + ((((size_t)EE * 32 + cfg) * 16 + ks) * 64 + lane) * 8));
            acc2[cf] = __builtin_amdgcn_mfma_f32_16x16x32_bf16(afrag, bfrag, acc2[cf], 0, 0, 0);
        }
    }
    // ---- epilogue: +b_self, relu, store ----
    #pragma unroll
    for (int cf = 0; cf < 16; cf++) {
        int col = ch * 256 + cf * 16 + lc;
        float bs = b_self[col];
        #pragma unroll
        for (int r = 0; r < 4; r++) {
            int row = r0 + rf * 16 + lk * 4 + r;
            float v = acc2[cf][r] + bs;
            v = v > 0.f ? v : 0.f;
            size_t gi = ((size_t)b * NN + row) * DD + col;
            if (TI == 0) out_bf16[gi] = f2b(v);
            else         out_f32[gi] = v;
        }
    }
}

extern "C" void kernel_launch(void* const* d_in, const int* in_sizes, int n_in,
                              void* d_out, int out_size, void* d_ws, size_t ws_size,
                              hipStream_t stream) {
    const float* node   = (const float*)d_in[0];
    const float* W_nw   = (const float*)d_in[1];
    const float* b_nw   = (const float*)d_in[2];
    const float* W_self = (const float*)d_in[3];
    const float* b_self = (const float*)d_in[4];
    const float* W_edge = (const float*)d_in[5];
    const int*   mask   = (const int*)d_in[6];
    const int*   adj    = (const int*)d_in[7];
    float* out = (float*)d_out;
    float* out_w = out + (size_t)BB * NN * DD;   // all_weight region [B][2][N]

    char* ws = (char*)d_ws;
    size_t off = 0;
    unsigned short* Wf    = (unsigned short*)(ws + off); off += (size_t)11 * DD * DD * 2;      // 5.77 MB
    unsigned short* wTf   = (unsigned short*)(ws + off); off += (size_t)BB * DD * NN * 2;      // 16.78 MB
    unsigned short* xb0   = (unsigned short*)(ws + off); off += (size_t)BB * NN * DD * 2;      // 16.78 MB
    unsigned short* xb1   = (unsigned short*)(ws + off); off += (size_t)BB * NN * DD * 2;      // 16.78 MB
    unsigned*       packed= (unsigned*)(ws + off);       off += (size_t)EE * BB * NN * 8 * 4;  // 5.24 MB
    float*          recip = (float*)(ws + off);          off += (size_t)BB * NN * 4;
    float*          w_buf = (float*)(ws + off);          off += (size_t)BB * NN * 4;

    k_wconv<<<dim3(1408), dim3(256), 0, stream>>>(W_edge, W_self, Wf);
    k_graph<<<dim3(16384), dim3(256), 0, stream>>>(adj, mask, packed, recip);

    // iteration 0
    k_gate<0><<<dim3(4096), dim3(256), 0, stream>>>(node, nullptr, W_nw, b_nw, w_buf, out_w);
    k_transf<0><<<dim3(2048), dim3(256), 0, stream>>>(node, nullptr, w_buf, wTf, xb0);
    k2_heavy<0><<<dim3(256), dim3(512), 0, stream>>>(wTf, xb0, Wf, packed, recip, b_self, xb1, nullptr);

    // iteration 1
    k_gate<1><<<dim3(4096), dim3(256), 0, stream>>>(nullptr, xb1, W_nw, b_nw, w_buf, out_w);
    k_transf<1><<<dim3(2048), dim3(256), 0, stream>>>(nullptr, xb1, w_buf, wTf, xb0 /*unused*/);
    k2_heavy<1><<<dim3(256), dim3(512), 0, stream>>>(wTf, xb1, Wf, packed, recip, b_self, nullptr, out);
}

// Round 3
// 794.844 us; speedup vs baseline: 3.0471x; 2.9741x over previous
//
#include <hip/hip_runtime.h>
#include <hip/hip_bf16.h>

#define BB 64
#define NN 256
#define DD 512
#define EE 10

typedef __bf16 bf16x8 __attribute__((ext_vector_type(8)));
typedef unsigned short ushort8v __attribute__((ext_vector_type(8)));
typedef unsigned int uint4v __attribute__((ext_vector_type(4)));
typedef float floatx4 __attribute__((ext_vector_type(4)));
typedef float floatx16 __attribute__((ext_vector_type(16)));

typedef __attribute__((address_space(3))) unsigned short lds_us;
typedef const __attribute__((address_space(1))) unsigned short glb_us;

__device__ __forceinline__ unsigned short f2b(float f) {
    union { float f; unsigned u; } x; x.f = f;
    unsigned r = x.u + 0x7FFFu + ((x.u >> 16) & 1u);
    return (unsigned short)(r >> 16);
}
__device__ __forceinline__ float b2f(unsigned short u) {
    union { unsigned u; float f; } x; x.u = ((unsigned)u) << 16;
    return x.f;
}

// ---------------- K0a: W_edge/W_self -> Wf in 32x32x16 MFMA-B fragment order.
// idx t = ((e*16+cfg32)*32+kstep)*64+lane; elem j = W[e][dout=cfg32*32+(lane&31)][k=kstep*16+(lane>>5)*8+j]
__global__ void k_wconv(const float* __restrict__ W_edge,
                        const float* __restrict__ W_self,
                        unsigned short* __restrict__ Wf) {
    int t = blockIdx.x * 256 + threadIdx.x;   // grid 1408 -> 360448 exact
    int lane  = t & 63;
    int kstep = (t >> 6) & 31;
    int cfg   = (t >> 11) & 15;
    int e     = t >> 15;                      // 0..10
    int dout = cfg * 32 + (lane & 31);
    int k    = kstep * 16 + (lane >> 5) * 8;
    const float* src = (e < EE) ? (W_edge + ((size_t)e * DD + dout) * DD + k)
                                : (W_self + (size_t)dout * DD + k);
    ushort8v o;
    #pragma unroll
    for (int j = 0; j < 8; j++) o[j] = f2b(src[j]);
    *(ushort8v*)(Wf + (size_t)t * 8) = o;
}

// ---------------- K0b: pack graph bits + recip(neigh). One block per (b,n).
__global__ void k_graph(const int* __restrict__ adj, const int* __restrict__ mask,
                        unsigned* __restrict__ packed, float* __restrict__ recip) {
    int b = blockIdx.x >> 8;
    int n = blockIdx.x & 255;
    int lane = threadIdx.x & 63;
    int wv   = threadIdx.x >> 6;   // 0..3
    int m = wv * 64 + lane;
    int ok = (mask[b * NN + n] != 0) & (mask[b * NN + m] != 0) & (m != n);
    __shared__ int cnt_s[4];
    int total = 0;
    #pragma unroll
    for (int e = 0; e < EE; e++) {
        int a = adj[(((size_t)e * BB + b) * NN + n) * NN + m];
        int bit = ok & (a != 0);
        unsigned long long bal = __ballot(bit);
        if (lane == 0) {
            unsigned* dst = packed + (((size_t)e * BB + b) * NN + n) * 8 + wv * 2;
            dst[0] = (unsigned)bal;
            dst[1] = (unsigned)(bal >> 32);
        }
        total += bit;
    }
    for (int off = 32; off; off >>= 1) total += __shfl_down(total, off);
    if (lane == 0) cnt_s[wv] = total;
    __syncthreads();
    if (threadIdx.x == 0) {
        int c = cnt_s[0] + cnt_s[1] + cnt_s[2] + cnt_s[3];
        recip[b * NN + n] = 1.0f / (float)(c < 1 ? 1 : c);
    }
}

// ---------------- K1a: gate w = sigmoid(node . W_nw + b). One wave per (b,n).
template<int TI>
__global__ void k_gate(const float* __restrict__ xf, const unsigned short* __restrict__ xbin,
                       const float* __restrict__ W_nw, const float* __restrict__ b_nw,
                       float* __restrict__ w_buf, float* __restrict__ w_out) {
    int idx = blockIdx.x * 4 + (threadIdx.x >> 6);
    int lane = threadIdx.x & 63;
    size_t base = (size_t)idx * DD + lane * 8;
    const floatx4* wp = (const floatx4*)(W_nw + lane * 8);
    floatx4 w0 = wp[0], w1 = wp[1];
    float s = 0.f;
    if (TI == 0) {
        const floatx4* xp = (const floatx4*)(xf + base);
        floatx4 a0 = xp[0], a1 = xp[1];
        #pragma unroll
        for (int j = 0; j < 4; j++) s += a0[j] * w0[j] + a1[j] * w1[j];
    } else {
        ushort8v u = *(const ushort8v*)(xbin + base);
        #pragma unroll
        for (int j = 0; j < 8; j++) {
            float wj = (j < 4) ? w0[j] : w1[j - 4];
            s += b2f(u[j]) * wj;
        }
    }
    for (int off = 32; off; off >>= 1) s += __shfl_down(s, off);
    if (lane == 0) {
        float v = 1.f / (1.f + __expf(-(s + b_nw[0])));
        w_buf[idx] = v;
        int b = idx >> 8, n = idx & 255;
        w_out[(b * 2 + TI) * NN + n] = v;
    }
}

// ---------------- K1b: build wTf (stage-1 B frags, 32x32x16 order) = w[b][m]*node[b][m][d].
// idx = ((b*16+mstep)*16+dblk32)*64+lane; elem j = wnode[b][mstep*16+(lane>>5)*8+j][dblk32*32+(lane&31)]
template<int TI>
__global__ void k_transf(const float* __restrict__ xf, const unsigned short* __restrict__ xbin,
                         const float* __restrict__ w_buf,
                         unsigned short* __restrict__ wTf, unsigned short* __restrict__ xb0) {
    int bid = blockIdx.x;              // 64*4*8 = 2048
    int b  = bid >> 5;
    int nt = (bid >> 3) & 3;           // 64-m slab
    int dt = bid & 7;                  // 64-d slab
    __shared__ float tile[64][65];
    __shared__ float ws[64];
    int j  = threadIdx.x & 63;         // d
    int i0 = threadIdx.x >> 6;
    if (threadIdx.x < 64) ws[threadIdx.x] = w_buf[b * NN + nt * 64 + threadIdx.x];
    #pragma unroll
    for (int ii = 0; ii < 16; ii++) {
        int i = i0 * 16 + ii;          // m local
        size_t gi = ((size_t)b * NN + nt * 64 + i) * DD + dt * 64 + j;
        float v = (TI == 0) ? xf[gi] : b2f(xbin[gi]);
        tile[i][j] = v;
        if (TI == 0) xb0[gi] = f2b(v);
    }
    __syncthreads();
    int lane = threadIdx.x & 63;
    int l31 = lane & 31, hi = lane >> 5;
    #pragma unroll
    for (int cc = 0; cc < 2; cc++) {
        int c = cc * 4 + (threadIdx.x >> 6);   // 0..7: (msl = c>>1, dbl = c&1)
        int msl = c >> 1, dbl = c & 1;
        ushort8v o;
        #pragma unroll
        for (int jj = 0; jj < 8; jj++) {
            int m_loc = msl * 16 + hi * 8 + jj;
            int d_loc = dbl * 32 + l31;
            o[jj] = f2b(tile[m_loc][d_loc] * ws[m_loc]);
        }
        size_t idx = (((size_t)b * 16 + nt * 4 + msl) * 16 + dt * 2 + dbl) * 64 + lane;
        *(ushort8v*)(wTf + idx * 8) = o;
    }
}

// ---------------- K2: fused heavy kernel, 32x32x16 MFMA, LDS-staged operands.
// Block: 512 thr = 8 waves. Tile: 128 rows (half a b) x 256 cols (ct half).
// Loop: dc (8 chunks of k=64) -> e (0..9 edges, 10 = self).
template<int TI>
__global__ __launch_bounds__(512, 2)
void k2_heavy(const unsigned short* __restrict__ wTf,   // 32x32 frag order
              const unsigned short* __restrict__ xb,    // [B][N][D] bf16 (self A)
              const unsigned short* __restrict__ Wf,    // 32x32 frag order [11]
              const unsigned* __restrict__ packed,      // [E][B][N][8]
              const float* __restrict__ recip,          // [B][N]
              const float* __restrict__ b_self,         // [D]
              unsigned short* __restrict__ out_bf16,    // t=0
              float* __restrict__ out_f32) {            // t=1
    __shared__ __attribute__((aligned(16))) unsigned short sWT[32 * 512];      // 32 KB
    __shared__ __attribute__((aligned(16))) unsigned short sWf[2][32 * 512];   // 64 KB
    __shared__ __attribute__((aligned(16))) unsigned short sT[128 * 76];       // 19 KB

    int bid = blockIdx.x;            // 256
    int xcd = bid & 7;
    int ct  = xcd >> 2;              // col half pinned per XCD group
    int rtile = (bid >> 3) * 4 + (xcd & 3);   // 0..127
    int b = rtile >> 1, h = rtile & 1;
    int w = threadIdx.x >> 6, lane = threadIdx.x & 63;
    int rh = w >> 2;                 // 64-row half of the 128-row tile
    int cq = w & 3;                  // 64-col quarter of the 256-col tile
    int rbT = rh * 2 + (cq >> 1);    // stage-1 32-row band (0..3)
    int cbT = cq & 1;                // stage-1 32-col half of the k-chunk
    int l31 = lane & 31, hi = lane >> 5;

    // recip for stage-1 output rows (C-layout rows of the wave's stage-1 frag)
    float rn[16];
    #pragma unroll
    for (int rg = 0; rg < 16; rg++) {
        int rloc = (rg & 3) + 8 * (rg >> 2) + 4 * hi;
        rn[rg] = recip[b * NN + h * 128 + rbT * 32 + rloc];
    }

    floatx16 acc2[2][2];
    #pragma unroll
    for (int i = 0; i < 2; i++)
        #pragma unroll
        for (int jj = 0; jj < 2; jj++)
            #pragma unroll
            for (int q = 0; q < 16; q++) acc2[i][jj][q] = 0.f;

    auto stage_sWf = [&](int e, int dc, int buf) {
        #pragma unroll
        for (int it = 0; it < 4; it++) {
            int c = it * 8 + w;                 // 0..31
            int cfl = c >> 2, kl = c & 3;
            const unsigned short* g = Wf +
                ((((size_t)e * 16 + ct * 8 + cfl) * 32 + dc * 4 + kl) * 64 + lane) * 8;
            __builtin_amdgcn_global_load_lds((glb_us*)g, (lds_us*)&sWf[buf][c * 512], 16, 0, 0);
        }
    };
    auto stage_sWT = [&](int dc) {
        #pragma unroll
        for (int it = 0; it < 4; it++) {
            int c = it * 8 + w;                 // 0..31: msl = c>>1, dbl = c&1
            int msl = c >> 1, dbl = c & 1;
            const unsigned short* g = wTf +
                ((((size_t)b * 16 + msl) * 16 + dc * 2 + dbl) * 64 + lane) * 8;
            __builtin_amdgcn_global_load_lds((glb_us*)g, (lds_us*)&sWT[c * 512], 16, 0, 0);
        }
    };

    // prime
    stage_sWT(0);
    stage_sWf(0, 0, 0);

    bf16x8 Bc[16];   // stage-1 B register cache (e-invariant within a dc)

    #pragma unroll 1
    for (int dc = 0; dc < 8; dc++) {
        #pragma unroll 1
        for (int e = 0; e <= EE; e++) {
            int s = dc * 11 + e;
            int cur = s & 1;
            // ---- top sync: prefetched LDS chunks ready everywhere ----
            asm volatile("s_waitcnt vmcnt(0)" ::: "memory");
            asm volatile("s_barrier" ::: "memory");

            unsigned pw[8];
            ushort8v xa[2][4];
            if (e < EE) {
                const uint4v* pp = (const uint4v*)(packed +
                    (((size_t)e * BB + b) * NN + h * 128 + rbT * 32 + l31) * 8);
                uint4v pa = pp[0], pb = pp[1];
                pw[0]=pa[0]; pw[1]=pa[1]; pw[2]=pa[2]; pw[3]=pa[3];
                pw[4]=pb[0]; pw[5]=pb[1]; pw[6]=pb[2]; pw[7]=pb[3];
            } else {
                #pragma unroll
                for (int ra = 0; ra < 2; ra++)
                    #pragma unroll
                    for (int ks = 0; ks < 4; ks++)
                        xa[ra][ks] = *(const ushort8v*)(xb +
                            ((size_t)(b * NN + h * 128 + rh * 64 + ra * 32 + l31)) * DD +
                            dc * 64 + ks * 16 + hi * 8);
            }
            // ---- prefetches for next step ----
            if (s < 87) {
                int ne = e + 1, ndc = dc;
                if (ne == 11) { ne = 0; ndc = dc + 1; }
                stage_sWf(ne, ndc, cur ^ 1);
            }
            if (e == 1 && dc < 7) stage_sWT(dc + 1);

            // ---- fill stage-1 B register cache at dc start ----
            if (e == 0) {
                #pragma unroll
                for (int ms = 0; ms < 16; ms++)
                    Bc[ms] = __builtin_bit_cast(bf16x8,
                        *(const ushort8v*)&sWT[((ms * 2 + cbT) * 64 + lane) * 8]);
            }

            if (e < EE) {
                // ---- stage 1: T chunk (128 x 64) = G_e @ wnode chunk ----
                floatx16 acc3;
                #pragma unroll
                for (int q = 0; q < 16; q++) acc3[q] = 0.f;
                #pragma unroll
                for (int ms = 0; ms < 16; ms++) {
                    unsigned byte = (pw[ms >> 1] >> ((((ms & 1) << 1) + hi) * 8)) & 0xFFu;
                    uint4v av;
                    #pragma unroll
                    for (int p = 0; p < 4; p++) {
                        unsigned b2 = (byte >> (2 * p)) & 3u;
                        av[p] = ((b2 & 1u) ? 0x3F80u : 0u) | ((b2 & 2u) ? 0x3F800000u : 0u);
                    }
                    acc3 = __builtin_amdgcn_mfma_f32_32x32x16_bf16(
                        __builtin_bit_cast(bf16x8, av), Bc[ms], acc3, 0, 0, 0);
                }
                // scale rows by recip, write bf16 to sT
                #pragma unroll
                for (int rg = 0; rg < 16; rg++) {
                    int rloc = rbT * 32 + (rg & 3) + 8 * (rg >> 2) + 4 * hi;
                    sT[rloc * 76 + cbT * 32 + l31] = f2b(acc3[rg] * rn[rg]);
                }
                // ---- mid sync: sT visible to all waves (lgkm only) ----
                asm volatile("s_waitcnt lgkmcnt(0)" ::: "memory");
                asm volatile("s_barrier" ::: "memory");
            }
            // ---- stage 2: acc2 += A(128x64) @ W chunk ----
            #pragma unroll
            for (int ks = 0; ks < 4; ks++) {
                bf16x8 bfr[2];
                #pragma unroll
                for (int cb = 0; cb < 2; cb++)
                    bfr[cb] = __builtin_bit_cast(bf16x8,
                        *(const ushort8v*)&sWf[cur][(((cq * 2 + cb) * 4 + ks) * 64 + lane) * 8]);
                #pragma unroll
                for (int ra = 0; ra < 2; ra++) {
                    bf16x8 afr;
                    if (e < EE)
                        afr = __builtin_bit_cast(bf16x8, *(const ushort8v*)
                            &sT[(rh * 64 + ra * 32 + l31) * 76 + ks * 16 + hi * 8]);
                    else
                        afr = __builtin_bit_cast(bf16x8, xa[ra][ks]);
                    #pragma unroll
                    for (int cb = 0; cb < 2; cb++)
                        acc2[ra][cb] = __builtin_amdgcn_mfma_f32_32x32x16_bf16(
                            afr, bfr[cb], acc2[ra][cb], 0, 0, 0);
                }
            }
        }
    }
    // ---- epilogue: +b_self, relu, store ----
    #pragma unroll
    for (int cb = 0; cb < 2; cb++) {
        int col = ct * 256 + (cq * 2 + cb) * 32 + l31;
        float bs = b_self[col];
        #pragma unroll
        for (int ra = 0; ra < 2; ra++) {
            #pragma unroll
            for (int rg = 0; rg < 16; rg++) {
                int row = h * 128 + rh * 64 + ra * 32 + (rg & 3) + 8 * (rg >> 2) + 4 * hi;
                float v = acc2[ra][cb][rg] + bs;
                v = v > 0.f ? v : 0.f;
                size_t gi = ((size_t)b * NN + row) * DD + col;
                if (TI == 0) out_bf16[gi] = f2b(v);
                else         out_f32[gi] = v;
            }
        }
    }
}

extern "C" void kernel_launch(void* const* d_in, const int* in_sizes, int n_in,
                              void* d_out, int out_size, void* d_ws, size_t ws_size,
                              hipStream_t stream) {
    const float* node   = (const float*)d_in[0];
    const float* W_nw   = (const float*)d_in[1];
    const float* b_nw   = (const float*)d_in[2];
    const float* W_self = (const float*)d_in[3];
    const float* b_self = (const float*)d_in[4];
    const float* W_edge = (const float*)d_in[5];
    const int*   mask   = (const int*)d_in[6];
    const int*   adj    = (const int*)d_in[7];
    float* out = (float*)d_out;
    float* out_w = out + (size_t)BB * NN * DD;   // all_weight region [B][2][N]

    char* ws = (char*)d_ws;
    size_t off = 0;
    unsigned short* Wf    = (unsigned short*)(ws + off); off += (size_t)11 * DD * DD * 2;      // 5.77 MB
    unsigned short* wTf   = (unsigned short*)(ws + off); off += (size_t)BB * DD * NN * 2;      // 16.78 MB
    unsigned short* xb0   = (unsigned short*)(ws + off); off += (size_t)BB * NN * DD * 2;      // 16.78 MB
    unsigned short* xb1   = (unsigned short*)(ws + off); off += (size_t)BB * NN * DD * 2;      // 16.78 MB
    unsigned*       packed= (unsigned*)(ws + off);       off += (size_t)EE * BB * NN * 8 * 4;  // 5.24 MB
    float*          recip = (float*)(ws + off);          off += (size_t)BB * NN * 4;
    float*          w_buf = (float*)(ws + off);          off += (size_t)BB * NN * 4;

    k_wconv<<<dim3(1408), dim3(256), 0, stream>>>(W_edge, W_self, Wf);
    k_graph<<<dim3(16384), dim3(256), 0, stream>>>(adj, mask, packed, recip);

    // iteration 0
    k_gate<0><<<dim3(4096), dim3(256), 0, stream>>>(node, nullptr, W_nw, b_nw, w_buf, out_w);
    k_transf<0><<<dim3(2048), dim3(256), 0, stream>>>(node, nullptr, w_buf, wTf, xb0);
    k2_heavy<0><<<dim3(256), dim3(512), 0, stream>>>(wTf, xb0, Wf, packed, recip, b_self, xb1, nullptr);

    // iteration 1
    k_gate<1><<<dim3(4096), dim3(256), 0, stream>>>(nullptr, xb1, W_nw, b_nw, w_buf, out_w);
    k_transf<1><<<dim3(2048), dim3(256), 0, stream>>>(nullptr, xb1, w_buf, wTf, xb0 /*unused*/);
    k2_heavy<1><<<dim3(256), dim3(512), 0, stream>>>(wTf, xb1, Wf, packed, recip, b_self, nullptr, out);
}

// Round 4
// 704.189 us; speedup vs baseline: 3.4394x; 1.1287x over previous
//
#include <hip/hip_runtime.h>
#include <hip/hip_bf16.h>

#define BB 64
#define NN 256
#define DD 512
#define EE 10

typedef __bf16 bf16x8 __attribute__((ext_vector_type(8)));
typedef unsigned short ushort8v __attribute__((ext_vector_type(8)));
typedef unsigned int uint4v __attribute__((ext_vector_type(4)));
typedef unsigned int uint2v __attribute__((ext_vector_type(2)));
typedef float floatx4 __attribute__((ext_vector_type(4)));
typedef float floatx16 __attribute__((ext_vector_type(16)));

typedef __attribute__((address_space(3))) unsigned short lds_us;
typedef const __attribute__((address_space(1))) unsigned short glb_us;

__device__ __forceinline__ unsigned short f2b(float f) {
    union { float f; unsigned u; } x; x.f = f;
    unsigned r = x.u + 0x7FFFu + ((x.u >> 16) & 1u);
    return (unsigned short)(r >> 16);
}
__device__ __forceinline__ float b2f(unsigned short u) {
    union { unsigned u; float f; } x; x.u = ((unsigned)u) << 16;
    return x.f;
}
// pack two rounded bf16 (hi=a, lo=b) from f32 bit patterns via byte-perm
__device__ __forceinline__ unsigned pack_bf16(float a, float b) {
    union { float f; unsigned u; } xa, xb2; xa.f = a; xb2.f = b;
    return __builtin_amdgcn_perm(xa.u + 0x8000u, xb2.u + 0x8000u, 0x07060302u);
}

// ---------------- K0a: W_edge/W_self -> Wf in 32x32x16 MFMA-B fragment order.
__global__ void k_wconv(const float* __restrict__ W_edge,
                        const float* __restrict__ W_self,
                        unsigned short* __restrict__ Wf) {
    int t = blockIdx.x * 256 + threadIdx.x;   // grid 1408 -> 360448 exact
    int lane  = t & 63;
    int kstep = (t >> 6) & 31;
    int cfg   = (t >> 11) & 15;
    int e     = t >> 15;                      // 0..10
    int dout = cfg * 32 + (lane & 31);
    int k    = kstep * 16 + (lane >> 5) * 8;
    const float* src = (e < EE) ? (W_edge + ((size_t)e * DD + dout) * DD + k)
                                : (W_self + (size_t)dout * DD + k);
    ushort8v o;
    #pragma unroll
    for (int j = 0; j < 8; j++) o[j] = f2b(src[j]);
    *(ushort8v*)(Wf + (size_t)t * 8) = o;
}

// ---------------- K0b: pack graph bits + recip(neigh). One block per (b,n).
__global__ void k_graph(const int* __restrict__ adj, const int* __restrict__ mask,
                        unsigned* __restrict__ packed, float* __restrict__ recip) {
    int b = blockIdx.x >> 8;
    int n = blockIdx.x & 255;
    int lane = threadIdx.x & 63;
    int wv   = threadIdx.x >> 6;   // 0..3
    int m = wv * 64 + lane;
    int ok = (mask[b * NN + n] != 0) & (mask[b * NN + m] != 0) & (m != n);
    __shared__ int cnt_s[4];
    int total = 0;
    #pragma unroll
    for (int e = 0; e < EE; e++) {
        int a = adj[(((size_t)e * BB + b) * NN + n) * NN + m];
        int bit = ok & (a != 0);
        unsigned long long bal = __ballot(bit);
        if (lane == 0) {
            unsigned* dst = packed + (((size_t)e * BB + b) * NN + n) * 8 + wv * 2;
            dst[0] = (unsigned)bal;
            dst[1] = (unsigned)(bal >> 32);
        }
        total += bit;
    }
    for (int off = 32; off; off >>= 1) total += __shfl_down(total, off);
    if (lane == 0) cnt_s[wv] = total;
    __syncthreads();
    if (threadIdx.x == 0) {
        int c = cnt_s[0] + cnt_s[1] + cnt_s[2] + cnt_s[3];
        recip[b * NN + n] = 1.0f / (float)(c < 1 ? 1 : c);
    }
}

// ---------------- K1a: gate w = sigmoid(node . W_nw + b). One wave per (b,n).
template<int TI>
__global__ void k_gate(const float* __restrict__ xf, const unsigned short* __restrict__ xbin,
                       const float* __restrict__ W_nw, const float* __restrict__ b_nw,
                       float* __restrict__ w_buf, float* __restrict__ w_out) {
    int idx = blockIdx.x * 4 + (threadIdx.x >> 6);
    int lane = threadIdx.x & 63;
    size_t base = (size_t)idx * DD + lane * 8;
    const floatx4* wp = (const floatx4*)(W_nw + lane * 8);
    floatx4 w0 = wp[0], w1 = wp[1];
    float s = 0.f;
    if (TI == 0) {
        const floatx4* xp = (const floatx4*)(xf + base);
        floatx4 a0 = xp[0], a1 = xp[1];
        #pragma unroll
        for (int j = 0; j < 4; j++) s += a0[j] * w0[j] + a1[j] * w1[j];
    } else {
        ushort8v u = *(const ushort8v*)(xbin + base);
        #pragma unroll
        for (int j = 0; j < 8; j++) {
            float wj = (j < 4) ? w0[j] : w1[j - 4];
            s += b2f(u[j]) * wj;
        }
    }
    for (int off = 32; off; off >>= 1) s += __shfl_down(s, off);
    if (lane == 0) {
        float v = 1.f / (1.f + __expf(-(s + b_nw[0])));
        w_buf[idx] = v;
        int b = idx >> 8, n = idx & 255;
        w_out[(b * 2 + TI) * NN + n] = v;
    }
}

// ---------------- K1b: build wTf (32x32 frag order) = w[b][m]*node[b][m][d], bf16.
template<int TI>
__global__ void k_transf(const float* __restrict__ xf, const unsigned short* __restrict__ xbin,
                         const float* __restrict__ w_buf,
                         unsigned short* __restrict__ wTf, unsigned short* __restrict__ xb0) {
    int bid = blockIdx.x;              // 64*4*8 = 2048
    int b  = bid >> 5;
    int nt = (bid >> 3) & 3;           // 64-m slab
    int dt = bid & 7;                  // 64-d slab
    __shared__ float tile[64][65];
    __shared__ float ws[64];
    int j  = threadIdx.x & 63;         // d
    int i0 = threadIdx.x >> 6;
    if (threadIdx.x < 64) ws[threadIdx.x] = w_buf[b * NN + nt * 64 + threadIdx.x];
    #pragma unroll
    for (int ii = 0; ii < 16; ii++) {
        int i = i0 * 16 + ii;          // m local
        size_t gi = ((size_t)b * NN + nt * 64 + i) * DD + dt * 64 + j;
        float v = (TI == 0) ? xf[gi] : b2f(xbin[gi]);
        tile[i][j] = v;
        if (TI == 0) xb0[gi] = f2b(v);
    }
    __syncthreads();
    int lane = threadIdx.x & 63;
    int l31 = lane & 31, hi = lane >> 5;
    #pragma unroll
    for (int cc = 0; cc < 2; cc++) {
        int c = cc * 4 + (threadIdx.x >> 6);   // 0..7: (msl = c>>1, dbl = c&1)
        int msl = c >> 1, dbl = c & 1;
        ushort8v o;
        #pragma unroll
        for (int jj = 0; jj < 8; jj++) {
            int m_loc = msl * 16 + hi * 8 + jj;
            int d_loc = dbl * 32 + l31;
            o[jj] = f2b(tile[m_loc][d_loc] * ws[m_loc]);
        }
        size_t idx = (((size_t)b * 16 + nt * 4 + msl) * 16 + dt * 2 + dbl) * 64 + lane;
        *(ushort8v*)(wTf + idx * 8) = o;
    }
}

// ---------------- K2: e-outer / dc-inner, T^T orientation, single-sT pipeline.
// Block 512 thr = 8 waves. Tile: 128 n (h half) x 256 dout (ct half). Grid 256.
template<int TI>
__global__ __launch_bounds__(512, 2)
void k2_heavy(const unsigned short* __restrict__ wTf,   // 32x32 frag order
              const unsigned short* __restrict__ xb,    // [B][N][D] bf16 (self A)
              const unsigned short* __restrict__ Wf,    // 32x32 frag order [11]
              const unsigned* __restrict__ packed,      // [E][B][N][8]
              const float* __restrict__ recip,          // [B][N]
              const float* __restrict__ b_self,         // [D]
              unsigned short* __restrict__ out_bf16,    // t=0
              float* __restrict__ out_f32) {            // t=1
    __shared__ __attribute__((aligned(16))) unsigned short sWT[2][32 * 512]; // 64 KB
    __shared__ __attribute__((aligned(16))) unsigned short sWf[2][32 * 512]; // 64 KB
    __shared__ __attribute__((aligned(16))) unsigned short sT[128 * 64];     // 16 KB

    int bid = blockIdx.x;            // b = bid&63 -> same-b quadrants share an XCD
    int b  = bid & 63;
    int q  = bid >> 6;               // 0..3
    int h  = q >> 1;                 // 128-n half
    int ct = q & 1;                  // 256-dout half
    int w = threadIdx.x >> 6, lane = threadIdx.x & 63;
    int l31 = lane & 31, hi = lane >> 5;
    // stage-1 role: one 32d x 32n frag of T^T
    int s1_d  = w & 1;               // d32 within dc-chunk
    int s1_nb = w >> 1;              // n32 band (0..3)
    int n1 = s1_nb * 32 + l31;       // block-local n (lane col in stage-1 C)
    float rn = recip[b * NN + h * 128 + n1];
    // stage-2 role: 64 n x 64 dout
    int nh2 = w & 1;                 // 64-n half
    int dh4 = w >> 1;                // 64-dout quarter (0..3)

    floatx16 acc2[2][2];             // [na][cb]
    #pragma unroll
    for (int i = 0; i < 2; i++)
        #pragma unroll
        for (int jj = 0; jj < 2; jj++)
            #pragma unroll
            for (int p = 0; p < 16; p++) acc2[i][jj][p] = 0.f;

    auto stage_sWT = [&](int dc, int buf) {
        #pragma unroll
        for (int it = 0; it < 4; it++) {
            int c = it * 8 + w;                 // 0..31: ms = c>>1, dbl = c&1
            const unsigned short* g = wTf +
                ((((size_t)b * 16 + (c >> 1)) * 16 + dc * 2 + (c & 1)) * 64 + lane) * 8;
            __builtin_amdgcn_global_load_lds((glb_us*)g, (lds_us*)&sWT[buf][c * 512], 16, 0, 0);
        }
    };
    auto stage_sWf = [&](int e, int dc, int buf) {
        #pragma unroll
        for (int it = 0; it < 4; it++) {
            int c = it * 8 + w;                 // 0..31: cf8 = c>>2, kk = c&3
            const unsigned short* g = Wf +
                ((((size_t)e * 16 + ct * 8 + (c >> 2)) * 32 + dc * 4 + (c & 3)) * 64 + lane) * 8;
            __builtin_amdgcn_global_load_lds((glb_us*)g, (lds_us*)&sWf[buf][c * 512], 16, 0, 0);
        }
    };

    // prime step 0
    stage_sWT(0, 0);
    stage_sWf(0, 0, 0);

    bf16x8 Bg[16];    // stage-1 B (expanded G bits), refreshed once per e
    int swz1 = (n1 & 7) << 3;

    #pragma unroll 1
    for (int s = 0; s < 88; s++) {
        int e = s >> 3, dc = s & 7, cur = s & 1;
        // ---- top sync: prefetched chunks ready; sT free for rewrite ----
        asm volatile("s_waitcnt vmcnt(0)" ::: "memory");
        asm volatile("s_barrier" ::: "memory");
        // ---- prefetch next step ----
        if (s < 87) {
            int ns = s + 1, ne = ns >> 3, ndc = ns & 7, nb = ns & 1;
            if (ne < EE) stage_sWT(ndc, nb);
            stage_sWf(ne, ndc, nb);
        }
        if (e < EE) {
            // ---- per-e: load packed bits + expand B fragments ----
            if (dc == 0) {
                const uint4v* pp = (const uint4v*)(packed +
                    (((size_t)e * BB + b) * NN + h * 128 + n1) * 8);
                uint4v pa = pp[0], pb = pp[1];
                unsigned pw[8] = {pa[0], pa[1], pa[2], pa[3], pb[0], pb[1], pb[2], pb[3]};
                #pragma unroll
                for (int ks = 0; ks < 16; ks++) {
                    int byi = ks * 2 + hi;
                    unsigned byte = (pw[byi >> 2] >> ((byi & 3) * 8)) & 0xFFu;
                    uint4v av;
                    #pragma unroll
                    for (int p = 0; p < 4; p++) {
                        unsigned t = (byte >> (2 * p)) & 3u;
                        unsigned u = (t | (t << 15)) & 0x10001u;
                        av[p] = u * 0x3F80u;
                    }
                    Bg[ks] = __builtin_bit_cast(bf16x8, av);
                }
            }
            // ---- stage 1: T^T frag (32d x 32n), K=256 over m ----
            floatx16 acc3;
            #pragma unroll
            for (int p = 0; p < 16; p++) acc3[p] = 0.f;
            #pragma unroll
            for (int ks = 0; ks < 16; ks++) {
                bf16x8 afr = __builtin_bit_cast(bf16x8,
                    *(const ushort8v*)&sWT[cur][(ks * 2 + s1_d) * 512 + lane * 8]);
                acc3 = __builtin_amdgcn_mfma_f32_32x32x16_bf16(afr, Bg[ks], acc3, 0, 0, 0);
            }
            // scale by recip(n) + pack + b64 writes into swizzled sT[n][d]
            #pragma unroll
            for (int qd = 0; qd < 4; qd++) {
                int d0 = s1_d * 32 + qd * 8 + hi * 4;
                uint2v pk;
                pk[0] = pack_bf16(acc3[qd * 4 + 1] * rn, acc3[qd * 4 + 0] * rn);
                pk[1] = pack_bf16(acc3[qd * 4 + 3] * rn, acc3[qd * 4 + 2] * rn);
                *(uint2v*)&sT[n1 * 64 + (d0 ^ swz1)] = pk;
            }
            // ---- mid sync: sT visible (LDS only) ----
            asm volatile("s_waitcnt lgkmcnt(0)" ::: "memory");
            asm volatile("s_barrier" ::: "memory");
            // ---- stage 2: acc2 += T(64n x 64d) @ W chunk ----
            #pragma unroll
            for (int kk = 0; kk < 4; kk++) {
                bf16x8 bfr[2];
                #pragma unroll
                for (int cb = 0; cb < 2; cb++)
                    bfr[cb] = __builtin_bit_cast(bf16x8, *(const ushort8v*)
                        &sWf[cur][((dh4 * 2 + cb) * 4 + kk) * 512 + lane * 8]);
                #pragma unroll
                for (int na = 0; na < 2; na++) {
                    int nloc = nh2 * 64 + na * 32 + l31;
                    int dloc = kk * 16 + hi * 8;
                    bf16x8 afr = __builtin_bit_cast(bf16x8, *(const ushort8v*)
                        &sT[nloc * 64 + (dloc ^ ((nloc & 7) << 3))]);
                    #pragma unroll
                    for (int cb = 0; cb < 2; cb++)
                        acc2[na][cb] = __builtin_amdgcn_mfma_f32_32x32x16_bf16(
                            afr, bfr[cb], acc2[na][cb], 0, 0, 0);
                }
            }
        } else {
            // ---- self path: A direct from xb ----
            #pragma unroll
            for (int kk = 0; kk < 4; kk++) {
                bf16x8 bfr[2];
                #pragma unroll
                for (int cb = 0; cb < 2; cb++)
                    bfr[cb] = __builtin_bit_cast(bf16x8, *(const ushort8v*)
                        &sWf[cur][((dh4 * 2 + cb) * 4 + kk) * 512 + lane * 8]);
                #pragma unroll
                for (int na = 0; na < 2; na++) {
                    bf16x8 afr = __builtin_bit_cast(bf16x8, *(const ushort8v*)(xb +
                        ((size_t)(b * NN + h * 128 + nh2 * 64 + na * 32 + l31)) * DD +
                        dc * 64 + kk * 16 + hi * 8));
                    #pragma unroll
                    for (int cb = 0; cb < 2; cb++)
                        acc2[na][cb] = __builtin_amdgcn_mfma_f32_32x32x16_bf16(
                            afr, bfr[cb], acc2[na][cb], 0, 0, 0);
                }
            }
        }
    }
    // ---- epilogue: +b_self, relu, store (C rows=n, cols=dout) ----
    #pragma unroll
    for (int cb = 0; cb < 2; cb++) {
        int col = ct * 256 + dh4 * 64 + cb * 32 + l31;
        float bs = b_self[col];
        #pragma unroll
        for (int na = 0; na < 2; na++) {
            #pragma unroll
            for (int rg = 0; rg < 16; rg++) {
                int row = h * 128 + nh2 * 64 + na * 32 + (rg & 3) + 8 * (rg >> 2) + 4 * hi;
                float v = acc2[na][cb][rg] + bs;
                v = v > 0.f ? v : 0.f;
                size_t gi = ((size_t)b * NN + row) * DD + col;
                if (TI == 0) out_bf16[gi] = f2b(v);
                else         out_f32[gi] = v;
            }
        }
    }
}

extern "C" void kernel_launch(void* const* d_in, const int* in_sizes, int n_in,
                              void* d_out, int out_size, void* d_ws, size_t ws_size,
                              hipStream_t stream) {
    const float* node   = (const float*)d_in[0];
    const float* W_nw   = (const float*)d_in[1];
    const float* b_nw   = (const float*)d_in[2];
    const float* W_self = (const float*)d_in[3];
    const float* b_self = (const float*)d_in[4];
    const float* W_edge = (const float*)d_in[5];
    const int*   mask   = (const int*)d_in[6];
    const int*   adj    = (const int*)d_in[7];
    float* out = (float*)d_out;
    float* out_w = out + (size_t)BB * NN * DD;   // all_weight region [B][2][N]

    char* ws = (char*)d_ws;
    size_t off = 0;
    unsigned short* Wf    = (unsigned short*)(ws + off); off += (size_t)11 * DD * DD * 2;      // 5.77 MB
    unsigned short* wTf   = (unsigned short*)(ws + off); off += (size_t)BB * DD * NN * 2;      // 16.78 MB
    unsigned short* xb0   = (unsigned short*)(ws + off); off += (size_t)BB * NN * DD * 2;      // 16.78 MB
    unsigned short* xb1   = (unsigned short*)(ws + off); off += (size_t)BB * NN * DD * 2;      // 16.78 MB
    unsigned*       packed= (unsigned*)(ws + off);       off += (size_t)EE * BB * NN * 8 * 4;  // 5.24 MB
    float*          recip = (float*)(ws + off);          off += (size_t)BB * NN * 4;
    float*          w_buf = (float*)(ws + off);          off += (size_t)BB * NN * 4;

    k_wconv<<<dim3(1408), dim3(256), 0, stream>>>(W_edge, W_self, Wf);
    k_graph<<<dim3(16384), dim3(256), 0, stream>>>(adj, mask, packed, recip);

    // iteration 0
    k_gate<0><<<dim3(4096), dim3(256), 0, stream>>>(node, nullptr, W_nw, b_nw, w_buf, out_w);
    k_transf<0><<<dim3(2048), dim3(256), 0, stream>>>(node, nullptr, w_buf, wTf, xb0);
    k2_heavy<0><<<dim3(256), dim3(512), 0, stream>>>(wTf, xb0, Wf, packed, recip, b_self, xb1, nullptr);

    // iteration 1
    k_gate<1><<<dim3(4096), dim3(256), 0, stream>>>(nullptr, xb1, W_nw, b_nw, w_buf, out_w);
    k_transf<1><<<dim3(2048), dim3(256), 0, stream>>>(nullptr, xb1, w_buf, wTf, xb0 /*unused*/);
    k2_heavy<1><<<dim3(256), dim3(512), 0, stream>>>(wTf, xb1, Wf, packed, recip, b_self, nullptr, out);
}